// Round 3
// baseline (963.479 us; speedup 1.0000x reference)
//
#include <hip/hip_runtime.h>
#include <hip/hip_bf16.h>
#include <math.h>

#define HEADS   6
#define DMODEL  1024
#define NPROJ   384
#define DSP     64
#define NPOOL   2048
#define NROWS   8192
#define TILE_M  64
#define KT      64
#define KEEP    16

#define LOG2E_F 1.44269504088896340f
#define LOG2E_D 1.4426950408889634
#define C2      14.4269504088896340f   /* 10*log2(e); |logit| provably < 10 */

#define NINF (-__builtin_inff())
#define IMAX 0x7fffffff

typedef __attribute__((ext_vector_type(8))) short  short8;
typedef __attribute__((ext_vector_type(4))) float  f32x4;

__device__ __forceinline__ bool bet_f(float v, int vi, float w, int wi) {
    return (v > w) || (v == w && vi < wi);
}
__device__ __forceinline__ bool bet_d(double v, int vi, double w, int wi) {
    return (v > w) || (v == w && vi < wi);
}
__device__ __forceinline__ unsigned short f2bf(float f) {   // RNE, no NaN inputs
    unsigned int u = __float_as_uint(f);
    return (unsigned short)((u + 0x7fffu + ((u >> 16) & 1u)) >> 16);
}
__device__ __forceinline__ float bf2f(unsigned short s) {
    return __uint_as_float(((unsigned int)s) << 16);
}
__device__ __forceinline__ unsigned int packbf2(float a, float b) {
    return (unsigned int)f2bf(a) | ((unsigned int)f2bf(b) << 16);
}

// ---------- named-scalar top-8 list machinery (NO private arrays => no scratch) ----------
#define DECL8(r) \
    float tv##r##0=NINF,tv##r##1=NINF,tv##r##2=NINF,tv##r##3=NINF, \
          tv##r##4=NINF,tv##r##5=NINF,tv##r##6=NINF,tv##r##7=NINF; \
    int   ti##r##0=IMAX,ti##r##1=IMAX,ti##r##2=IMAX,ti##r##3=IMAX, \
          ti##r##4=IMAX,ti##r##5=IMAX,ti##r##6=IMAX,ti##r##7=IMAX;

#define CSW8(r,hi,lo) { \
    const bool sw_ = bet_f(tv##r##lo,ti##r##lo,tv##r##hi,ti##r##hi); \
    const float tf_ = tv##r##hi; const int tj_ = ti##r##hi; \
    tv##r##hi = sw_?tv##r##lo:tv##r##hi; ti##r##hi = sw_?ti##r##lo:ti##r##hi; \
    tv##r##lo = sw_?tf_:tv##r##lo;       ti##r##lo = sw_?tj_:ti##r##lo; }

#define INS8(r,W,CI) \
    if (bet_f(W,CI,tv##r##7,ti##r##7)) { \
        tv##r##7=(W); ti##r##7=(CI); \
        CSW8(r,6,7) CSW8(r,5,6) CSW8(r,4,5) CSW8(r,3,4) \
        CSW8(r,2,3) CSW8(r,1,2) CSW8(r,0,1) }

// in-wave 16-lane tournament: global top-16 of one row from 16 sorted 8-lists.
#define TOURN(r, ROW) { \
    int slot_ = IMAX; \
    for (int k_=0;k_<16;++k_) { \
        float v_ = tv##r##0; int ix_ = ti##r##0; \
        { float ov=__shfl_xor(v_,1,64); int oj=__shfl_xor(ix_,1,64); if (bet_f(ov,oj,v_,ix_)){v_=ov;ix_=oj;} } \
        { float ov=__shfl_xor(v_,2,64); int oj=__shfl_xor(ix_,2,64); if (bet_f(ov,oj,v_,ix_)){v_=ov;ix_=oj;} } \
        { float ov=__shfl_xor(v_,4,64); int oj=__shfl_xor(ix_,4,64); if (bet_f(ov,oj,v_,ix_)){v_=ov;ix_=oj;} } \
        { float ov=__shfl_xor(v_,8,64); int oj=__shfl_xor(ix_,8,64); if (bet_f(ov,oj,v_,ix_)){v_=ov;ix_=oj;} } \
        const bool won_ = (ix_ == ti##r##0); \
        tv##r##0 = won_?tv##r##1:tv##r##0; ti##r##0 = won_?ti##r##1:ti##r##0; \
        tv##r##1 = won_?tv##r##2:tv##r##1; ti##r##1 = won_?ti##r##2:ti##r##1; \
        tv##r##2 = won_?tv##r##3:tv##r##2; ti##r##2 = won_?ti##r##3:ti##r##2; \
        tv##r##3 = won_?tv##r##4:tv##r##3; ti##r##3 = won_?ti##r##4:ti##r##3; \
        tv##r##4 = won_?tv##r##5:tv##r##4; ti##r##4 = won_?ti##r##5:ti##r##4; \
        tv##r##5 = won_?tv##r##6:tv##r##5; ti##r##5 = won_?ti##r##6:ti##r##5; \
        tv##r##6 = won_?tv##r##7:tv##r##6; ti##r##6 = won_?ti##r##7:ti##r##6; \
        tv##r##7 = won_?NINF:tv##r##7;     ti##r##7 = won_?IMAX:ti##r##7; \
        slot_ = (m==k_)?ix_:slot_; \
    } \
    ridx16[(ROW)*16 + m] = slot_; }

// double-precision named top-8 (phase 4)
#define CSWD(hi,lo) { \
    const bool sw_ = bet_d(dv##lo,di##lo,dv##hi,di##hi); \
    const double td_ = dv##hi; const int tj_ = di##hi; \
    dv##hi = sw_?dv##lo:dv##hi; di##hi = sw_?di##lo:di##hi; \
    dv##lo = sw_?td_:dv##lo;    di##lo = sw_?tj_:di##lo; }

#define INS8D(W,CI) \
    if (bet_d(W,CI,dv7,di7)) { dv7=(W); di7=(CI); \
        CSWD(6,7) CSWD(5,6) CSWD(4,5) CSWD(3,4) CSWD(2,3) CSWD(1,2) CSWD(0,1) }

// ======================= Kernel 0: pool prep =======================
// Normalize pools 0..3 of emb (8192 rows), fold in LOG2E, pack bf16 -> d_ws.
__global__ __launch_bounds__(256)
void prep_k(const float* __restrict__ emb, ushort* __restrict__ ebf)
{
    const int row = blockIdx.x*256 + threadIdx.x;   // 0..8191 (pools fqk,fv,rqk,rv)
    const float* src = emb + (size_t)row*DSP;
    float ss = 0.f;
    #pragma unroll
    for (int g=0; g<16; ++g) {
        const float4 v = *(const float4*)(src + g*4);
        ss += v.x*v.x + v.y*v.y + v.z*v.z + v.w*v.w;
    }
    const float inv = LOG2E_F / fmaxf(sqrtf(ss), 1e-12f);
    ushort* dst = ebf + (size_t)row*DSP;
    #pragma unroll
    for (int g=0; g<8; ++g) {
        const float4 a = *(const float4*)(src + g*8);
        const float4 b = *(const float4*)(src + g*8 + 4);
        uint4 o;
        o.x = packbf2(a.x*inv, a.y*inv);
        o.y = packbf2(a.z*inv, a.w*inv);
        o.z = packbf2(b.x*inv, b.y*inv);
        o.w = packbf2(b.z*inv, b.w*inv);
        *(uint4*)(dst + g*8) = o;
    }
}

// ======================= Kernel 1: fp64 VALU projection (R6-verified) =======================
// h written into the block's own output region:
//   h_hi f32 [64][64] at out+obase, h_lo bf16 [64][64] at out+obase+4096 floats.
#define PJROW(i) \
    a##i##0 = fma(xd##i, wd0, a##i##0); a##i##1 = fma(xd##i, wd1, a##i##1); \
    a##i##2 = fma(xd##i, wd2, a##i##2); a##i##3 = fma(xd##i, wd3, a##i##3);

#define EPI(i) { \
    const double v0_=a##i##0+bj0, v1_=a##i##1+bj1, v2_=a##i##2+bj2, v3_=a##i##3+bj3; \
    float4 hv; ushort4 lv; \
    hv.x=(float)v0_; hv.y=(float)v1_; hv.z=(float)v2_; hv.w=(float)v3_; \
    lv.x=f2bf((float)(v0_-(double)hv.x)); lv.y=f2bf((float)(v1_-(double)hv.y)); \
    lv.z=f2bf((float)(v2_-(double)hv.z)); lv.w=f2bf((float)(v3_-(double)hv.w)); \
    *(float4*) &hhi[(size_t)(rg*4+i)*64 + cg*4] = hv; \
    *(ushort4*)&hlo[(size_t)(rg*4+i)*64 + cg*4] = lv; }

__global__ __launch_bounds__(256, 3)
void proj_k(const float* __restrict__ x, const float* __restrict__ Wm,
            const float* __restrict__ bb, float* __restrict__ out)
{
    __shared__ __align__(16) float x_t[64*68];   // [k][row]
    __shared__ __align__(16) float w_t[64*68];   // [k][col]

    const int t    = threadIdx.x;
    const int cg   = t & 15;
    const int rg   = t >> 4;
    const int head = blockIdx.y;
    const int row0 = blockIdx.x * TILE_M;
    const size_t obase = ((size_t)head*NROWS + row0) * (size_t)NPOOL;

    double a00=0,a01=0,a02=0,a03=0, a10=0,a11=0,a12=0,a13=0,
           a20=0,a21=0,a22=0,a23=0, a30=0,a31=0,a32=0,a33=0;

    const int xr = t >> 2;        // 0..63 row
    const int xq = t & 3;         // k quarter (16 k's)
    const int wr = t >> 4;        // 0..15 base k-row for W
    const float* wbase = Wm + head*64 + cg*4;

    float4 xv0,xv1,xv2,xv3, wv0,wv1,wv2,wv3;
    {
        const float* xsrc = x + (size_t)(row0+xr)*DMODEL + xq*16;
        xv0 = *(const float4*)(xsrc);     xv1 = *(const float4*)(xsrc + 4);
        xv2 = *(const float4*)(xsrc + 8); xv3 = *(const float4*)(xsrc + 12);
        wv0 = *(const float4*)(wbase + (size_t)(wr     )*NPROJ);
        wv1 = *(const float4*)(wbase + (size_t)(wr + 16)*NPROJ);
        wv2 = *(const float4*)(wbase + (size_t)(wr + 32)*NPROJ);
        wv3 = *(const float4*)(wbase + (size_t)(wr + 48)*NPROJ);
    }

    for (int kk = 0; kk < DMODEL; kk += KT) {
        __syncthreads();   // prev tile's LDS reads done
        {
            const int k0 = xq*16;
            x_t[(k0+ 0)*68+xr]=xv0.x; x_t[(k0+ 1)*68+xr]=xv0.y; x_t[(k0+ 2)*68+xr]=xv0.z; x_t[(k0+ 3)*68+xr]=xv0.w;
            x_t[(k0+ 4)*68+xr]=xv1.x; x_t[(k0+ 5)*68+xr]=xv1.y; x_t[(k0+ 6)*68+xr]=xv1.z; x_t[(k0+ 7)*68+xr]=xv1.w;
            x_t[(k0+ 8)*68+xr]=xv2.x; x_t[(k0+ 9)*68+xr]=xv2.y; x_t[(k0+10)*68+xr]=xv2.z; x_t[(k0+11)*68+xr]=xv2.w;
            x_t[(k0+12)*68+xr]=xv3.x; x_t[(k0+13)*68+xr]=xv3.y; x_t[(k0+14)*68+xr]=xv3.z; x_t[(k0+15)*68+xr]=xv3.w;
            *(float4*)&w_t[(wr     )*68 + cg*4] = wv0;
            *(float4*)&w_t[(wr + 16)*68 + cg*4] = wv1;
            *(float4*)&w_t[(wr + 32)*68 + cg*4] = wv2;
            *(float4*)&w_t[(wr + 48)*68 + cg*4] = wv3;
        }
        __syncthreads();
        if (kk + KT < DMODEL) {   // prefetch next tile
            const float* xsrc = x + (size_t)(row0+xr)*DMODEL + (kk+KT) + xq*16;
            xv0 = *(const float4*)(xsrc);     xv1 = *(const float4*)(xsrc + 4);
            xv2 = *(const float4*)(xsrc + 8); xv3 = *(const float4*)(xsrc + 12);
            wv0 = *(const float4*)(wbase + (size_t)(kk+KT + wr     )*NPROJ);
            wv1 = *(const float4*)(wbase + (size_t)(kk+KT + wr + 16)*NPROJ);
            wv2 = *(const float4*)(wbase + (size_t)(kk+KT + wr + 32)*NPROJ);
            wv3 = *(const float4*)(wbase + (size_t)(kk+KT + wr + 48)*NPROJ);
        }
        #pragma unroll 4
        for (int k=0;k<KT;k++) {
            const float4 xf = *(const float4*)&x_t[k*68 + rg*4];
            const float4 wf = *(const float4*)&w_t[k*68 + cg*4];
            const double xd0=(double)xf.x, xd1=(double)xf.y, xd2=(double)xf.z, xd3=(double)xf.w;
            const double wd0=(double)wf.x, wd1=(double)wf.y, wd2=(double)wf.z, wd3=(double)wf.w;
            PJROW(0) PJROW(1) PJROW(2) PJROW(3)
        }
    }

    float*  hhi = out + obase;                       // [64][64] f32
    ushort* hlo = (ushort*)(out + obase + 4096);     // [64][64] bf16
    const double bj0=(double)bb[head*64+cg*4+0], bj1=(double)bb[head*64+cg*4+1];
    const double bj2=(double)bb[head*64+cg*4+2], bj3=(double)bb[head*64+cg*4+3];
    EPI(0) EPI(1) EPI(2) EPI(3)
}

// ======================= Kernel 2: router =======================
__global__ __launch_bounds__(256, 3)
void route_k(const float* __restrict__ emb, const ushort* __restrict__ ebf,
             float* __restrict__ out)
{
    __shared__ int    ridx16[64*16];                 // 4096 B
    __shared__ float  zbuf[64];
    __shared__ double rv[64*17];                     // 8704 B
    __shared__ __align__(8) float final8[64*16];     // 4096 B

    const int t    = threadIdx.x;
    const int lane = t & 63, wv = t >> 6;
    const int m    = lane & 15, q = lane >> 4;
    const int head = blockIdx.y;
    const int row0 = blockIdx.x * TILE_M;
    const size_t obase = ((size_t)head*NROWS + row0) * (size_t)NPOOL;

    int psel = 0;                 // pools: [fqk,fqk,fv,rqk,rqk,rv]
    if (head >= 2) psel = 1;
    if (head >= 3) psel = 2;
    if (head >= 5) psel = 3;
    const float*  epool = emb + (size_t)psel * NPOOL * DSP;
    const ushort* ebase = ebf + (size_t)psel * NPOOL * DSP;

    // ---- A fragments: h rows of this wave, bf16, from h_hi scratch ----
    union FragU { unsigned int u[4]; short8 s; };
    FragU A0, A1;
    {
        const float* hr = out + obase + (size_t)(wv*16 + m)*64 + q*8;
        const float4 a0 = *(const float4*)(hr);
        const float4 a1 = *(const float4*)(hr + 4);
        const float4 a2 = *(const float4*)(hr + 32);
        const float4 a3 = *(const float4*)(hr + 36);
        A0.u[0]=packbf2(a0.x,a0.y); A0.u[1]=packbf2(a0.z,a0.w);
        A0.u[2]=packbf2(a1.x,a1.y); A0.u[3]=packbf2(a1.z,a1.w);
        A1.u[0]=packbf2(a2.x,a2.y); A1.u[1]=packbf2(a2.z,a2.w);
        A1.u[2]=packbf2(a3.x,a3.y); A1.u[3]=packbf2(a3.z,a3.w);
    }

    // ---- Phase 1: MFMA logits, Z, per-lane top-8; B-frags = prepacked bf16 ----
    DECL8(0) DECL8(1) DECL8(2) DECL8(3)
    float zacc0=0.f, zacc1=0.f, zacc2=0.f, zacc3=0.f;

    #pragma unroll 1
    for (int it=0; it<128; ++it) {
        const int cidx = it*16 + m;                 // e row this lane needs
        const ushort* ep = ebase + (size_t)cidx*DSP + q*8;
        const short8 B0 = *(const short8*)(ep);
        const short8 B1 = *(const short8*)(ep + 32);

        f32x4 cc = {0.f,0.f,0.f,0.f};
        cc = __builtin_amdgcn_mfma_f32_16x16x32_bf16(A0.s, B0, cc, 0, 0, 0);
        cc = __builtin_amdgcn_mfma_f32_16x16x32_bf16(A1.s, B1, cc, 0, 0, 0);

        // raw v_exp_f32: args are in [-25,-4], always normal -> bit-identical to
        // libm exp2f here, but 1 instr instead of the compiler's guarded expansion.
        { const float w_ = cc[0]; zacc0 += __builtin_amdgcn_exp2f(w_ - C2); INS8(0, w_, cidx) }
        { const float w_ = cc[1]; zacc1 += __builtin_amdgcn_exp2f(w_ - C2); INS8(1, w_, cidx) }
        { const float w_ = cc[2]; zacc2 += __builtin_amdgcn_exp2f(w_ - C2); INS8(2, w_, cidx) }
        { const float w_ = cc[3]; zacc3 += __builtin_amdgcn_exp2f(w_ - C2); INS8(3, w_, cidx) }
    }

    // ---- Z reduce over the 16 col-lanes of each row ----
    { float z=zacc0; z+=__shfl_xor(z,1,64); z+=__shfl_xor(z,2,64); z+=__shfl_xor(z,4,64); z+=__shfl_xor(z,8,64); if(m==0) zbuf[wv*16+q*4+0]=z; }
    { float z=zacc1; z+=__shfl_xor(z,1,64); z+=__shfl_xor(z,2,64); z+=__shfl_xor(z,4,64); z+=__shfl_xor(z,8,64); if(m==0) zbuf[wv*16+q*4+1]=z; }
    { float z=zacc2; z+=__shfl_xor(z,1,64); z+=__shfl_xor(z,2,64); z+=__shfl_xor(z,4,64); z+=__shfl_xor(z,8,64); if(m==0) zbuf[wv*16+q*4+2]=z; }
    { float z=zacc3; z+=__shfl_xor(z,1,64); z+=__shfl_xor(z,2,64); z+=__shfl_xor(z,4,64); z+=__shfl_xor(z,8,64); if(m==0) zbuf[wv*16+q*4+3]=z; }

    // ---- in-wave tournament: per-row top-16 into ridx16 (sorted desc) ----
    TOURN(0, wv*16 + q*4 + 0)
    TOURN(1, wv*16 + q*4 + 1)
    TOURN(2, wv*16 + q*4 + 2)
    TOURN(3, wv*16 + q*4 + 3)
    __syncthreads();

    // ---- Phase 3: fp64 rescore of the 16 candidates per row ----
    {
        const int row = t >> 2, q4 = t & 3;   // 4 candidates per thread
        const int ix0 = ridx16[row*16 + q4*4 + 0];
        const int ix1 = ridx16[row*16 + q4*4 + 1];
        const int ix2 = ridx16[row*16 + q4*4 + 2];
        const int ix3 = ridx16[row*16 + q4*4 + 3];
        const float* ep0 = epool + (size_t)ix0*DSP;
        const float* ep1 = epool + (size_t)ix1*DSP;
        const float* ep2 = epool + (size_t)ix2*DSP;
        const float* ep3 = epool + (size_t)ix3*DSP;
        const float*  hhr = out + obase + (size_t)row*64;
        const ushort* hlr = (const ushort*)(out + obase + 4096) + (size_t)row*64;
        double nn0=0,nn1=0,nn2=0,nn3=0, dd0=0,dd1=0,dd2=0,dd3=0;
        #pragma unroll 1
        for (int k4=0; k4<DSP; k4+=4) {
            const double h0 = (double)hhr[k4+0] + (double)bf2f(hlr[k4+0]);
            const double h1 = (double)hhr[k4+1] + (double)bf2f(hlr[k4+1]);
            const double h2 = (double)hhr[k4+2] + (double)bf2f(hlr[k4+2]);
            const double h3 = (double)hhr[k4+3] + (double)bf2f(hlr[k4+3]);
            #define RS(s) { const float4 e_ = *(const float4*)(ep##s + k4); \
                const double e0_=(double)e_.x, e1_=(double)e_.y, e2_=(double)e_.z, e3_=(double)e_.w; \
                nn##s += e0_*e0_ + e1_*e1_ + e2_*e2_ + e3_*e3_; \
                dd##s += h0*e0_ + h1*e1_ + h2*e2_ + h3*e3_; }
            RS(0) RS(1) RS(2) RS(3)
            #undef RS
        }
        rv[row*17 + q4*4 + 0] = dd0 / fmax(sqrt(nn0), 1e-12);
        rv[row*17 + q4*4 + 1] = dd1 / fmax(sqrt(nn1), 1e-12);
        rv[row*17 + q4*4 + 2] = dd2 / fmax(sqrt(nn2), 1e-12);
        rv[row*17 + q4*4 + 3] = dd3 / fmax(sqrt(nn3), 1e-12);
    }
    __syncthreads();

    // ---- Phase 5a: coalesced zero-fill of the whole output tile ----
    // Issued BEFORE phase 4 so the stores drain under phase-4's VALU work.
    // (hhi/hlo scratch already consumed by phases 1 & 3.)
    {
        #pragma unroll 1
        for (int rr=0; rr<16; ++rr) {
            float* orow = out + obase + (size_t)(wv*16 + rr)*NPOOL;
            #pragma unroll
            for (int j=0;j<8;j++)
                *(float4*)&orow[(j*64 + lane)*4] = make_float4(0.f,0.f,0.f,0.f);
        }
    }

    // ---- Phase 4: fp64 top-8 select (named scalars), normalize, stash in LDS ----
    if (t < 64) {
        const float Zg = zbuf[t];
        double dv0=-INFINITY,dv1=-INFINITY,dv2=-INFINITY,dv3=-INFINITY,
               dv4=-INFINITY,dv5=-INFINITY,dv6=-INFINITY,dv7=-INFINITY;
        int    di0=IMAX,di1=IMAX,di2=IMAX,di3=IMAX,di4=IMAX,di5=IMAX,di6=IMAX,di7=IMAX;
        #pragma unroll 1
        for (int s=0;s<KEEP;s++) {
            const double v_  = rv[t*17 + s];
            const int    ix_ = ridx16[t*16 + s];
            INS8D(v_, ix_)
        }
        float denom = 1e-8f * Zg;
        const float ov0 = __builtin_amdgcn_exp2f((float)(dv0*LOG2E_D) - C2); denom += ov0;
        const float ov1 = __builtin_amdgcn_exp2f((float)(dv1*LOG2E_D) - C2); denom += ov1;
        const float ov2 = __builtin_amdgcn_exp2f((float)(dv2*LOG2E_D) - C2); denom += ov2;
        const float ov3 = __builtin_amdgcn_exp2f((float)(dv3*LOG2E_D) - C2); denom += ov3;
        const float ov4 = __builtin_amdgcn_exp2f((float)(dv4*LOG2E_D) - C2); denom += ov4;
        const float ov5 = __builtin_amdgcn_exp2f((float)(dv5*LOG2E_D) - C2); denom += ov5;
        const float ov6 = __builtin_amdgcn_exp2f((float)(dv6*LOG2E_D) - C2); denom += ov6;
        const float ov7 = __builtin_amdgcn_exp2f((float)(dv7*LOG2E_D) - C2); denom += ov7;
        const float rd = 1.0f / denom;
        float2 p;
        p.x=ov0*rd; p.y=__int_as_float(di0); *(float2*)&final8[t*16 +  0] = p;
        p.x=ov1*rd; p.y=__int_as_float(di1); *(float2*)&final8[t*16 +  2] = p;
        p.x=ov2*rd; p.y=__int_as_float(di2); *(float2*)&final8[t*16 +  4] = p;
        p.x=ov3*rd; p.y=__int_as_float(di3); *(float2*)&final8[t*16 +  6] = p;
        p.x=ov4*rd; p.y=__int_as_float(di4); *(float2*)&final8[t*16 +  8] = p;
        p.x=ov5*rd; p.y=__int_as_float(di5); *(float2*)&final8[t*16 + 10] = p;
        p.x=ov6*rd; p.y=__int_as_float(di6); *(float2*)&final8[t*16 + 12] = p;
        p.x=ov7*rd; p.y=__int_as_float(di7); *(float2*)&final8[t*16 + 14] = p;
    }
    __syncthreads();   // drains 5a zero-stores (vmcnt 0) + final8 LDS stores

    // ---- Phase 5b: scatter the 8 values per row (after zeros are ack'd in L2) ----
    if (t < 64) {
        float* orow = out + obase + (size_t)t*NPOOL;
        #pragma unroll
        for (int s=0;s<8;s++) {
            const float pv = final8[t*16 + 2*s];
            const int   pi = __float_as_int(final8[t*16 + 2*s + 1]);
            orow[pi] = pv;
        }
    }
}

extern "C" void kernel_launch(void* const* d_in, const int* in_sizes, int n_in,
                              void* d_out, int out_size, void* d_ws, size_t ws_size,
                              hipStream_t stream) {
    (void)in_sizes; (void)n_in; (void)ws_size; (void)out_size;
    const float* x   = (const float*)d_in[0];
    const float* Wm  = (const float*)d_in[1];
    const float* bb  = (const float*)d_in[2];
    const float* emb = (const float*)d_in[3];
    float*  out = (float*)d_out;
    ushort* ebf = (ushort*)d_ws;          // 4*2048*64 bf16 = 1 MB scratch
    dim3 grid(NROWS / TILE_M, HEADS);
    prep_k <<<32, 256, 0, stream>>>(emb, ebf);
    proj_k <<<grid, dim3(256), 0, stream>>>(x, Wm, bb, out);
    route_k<<<grid, dim3(256), 0, stream>>>(emb, ebf, out);
}

// Round 4
// 804.688 us; speedup vs baseline: 1.1973x; 1.1973x over previous
//
#include <hip/hip_runtime.h>
#include <hip/hip_bf16.h>
#include <math.h>

#define HEADS   6
#define DMODEL  1024
#define NPROJ   384
#define DSP     64
#define NPOOL   2048
#define NROWS   8192
#define TILE_M  64
#define KT      64
#define KEEP    16

#define LOG2E_F 1.44269504088896340f
#define LOG2E_D 1.4426950408889634
#define C2      14.4269504088896340f   /* 10*log2(e); |logit| provably < 10 */

#define NINF (-__builtin_inff())
#define IMAX 0x7fffffff

typedef __attribute__((ext_vector_type(8))) short  short8;
typedef __attribute__((ext_vector_type(4))) float  f32x4;

__device__ __forceinline__ bool bet_d(double v, int vi, double w, int wi) {
    return (v > w) || (v == w && vi < wi);
}
__device__ __forceinline__ unsigned short f2bf(float f) {   // RNE, no NaN inputs
    unsigned int u = __float_as_uint(f);
    return (unsigned short)((u + 0x7fffu + ((u >> 16) & 1u)) >> 16);
}
__device__ __forceinline__ float bf2f(unsigned short s) {
    return __uint_as_float(((unsigned int)s) << 16);
}
__device__ __forceinline__ unsigned int packbf2(float a, float b) {
    return (unsigned int)f2bf(a) | ((unsigned int)f2bf(b) << 16);
}

// ---------- packed u32 top-8 machinery ----------
// Candidate packed as: [21 value bits | 11 bits of (2047-idx)].
// Value bits = monotonic (order-preserving) uint transform of the f32 logit,
// truncated to 21 bits. Larger packed == better candidate (higher value,
// ties -> smaller index), so all list ops are plain unsigned min/max.
// Truncation (2^-21 rel) only perturbs the 16-candidate set boundary, far
// below the bf16-MFMA logit noise the margin already absorbs; final top-8
// comes from the fp64 rescore of the candidates.
#define DECL8P(r) \
    unsigned tp##r##0=0u,tp##r##1=0u,tp##r##2=0u,tp##r##3=0u, \
             tp##r##4=0u,tp##r##5=0u,tp##r##6=0u,tp##r##7=0u;

#define CSWP(r,hi,lo) { const unsigned a_=tp##r##hi, b_=tp##r##lo; \
    tp##r##hi = a_>b_?a_:b_; tp##r##lo = a_>b_?b_:a_; }

#define INS8P(r,P) \
    if ((P) > tp##r##7) { tp##r##7=(P); \
        CSWP(r,6,7) CSWP(r,5,6) CSWP(r,4,5) CSWP(r,3,4) \
        CSWP(r,2,3) CSWP(r,1,2) CSWP(r,0,1) }

// in-wave 16-lane tournament: global top-16 of one row from 16 sorted 8-lists.
// All 128 packed values are unique (each pool index occurs in exactly one
// lane's list), so the winner test (v_ == my0_) fires on exactly one lane.
#define TOURNP(r, ROW) { \
    unsigned slot_ = 0u; \
    for (int k_=0;k_<16;++k_) { \
        const unsigned my0_ = tp##r##0; \
        unsigned v_ = my0_; \
        { const unsigned o_=(unsigned)__shfl_xor((int)v_,1,64); v_ = v_>o_?v_:o_; } \
        { const unsigned o_=(unsigned)__shfl_xor((int)v_,2,64); v_ = v_>o_?v_:o_; } \
        { const unsigned o_=(unsigned)__shfl_xor((int)v_,4,64); v_ = v_>o_?v_:o_; } \
        { const unsigned o_=(unsigned)__shfl_xor((int)v_,8,64); v_ = v_>o_?v_:o_; } \
        const bool won_ = (v_ == my0_); \
        tp##r##0 = won_?tp##r##1:tp##r##0; \
        tp##r##1 = won_?tp##r##2:tp##r##1; \
        tp##r##2 = won_?tp##r##3:tp##r##2; \
        tp##r##3 = won_?tp##r##4:tp##r##3; \
        tp##r##4 = won_?tp##r##5:tp##r##4; \
        tp##r##5 = won_?tp##r##6:tp##r##5; \
        tp##r##6 = won_?tp##r##7:tp##r##6; \
        tp##r##7 = won_?0u:tp##r##7; \
        slot_ = (m==k_)?v_:slot_; \
    } \
    ridx16[(ROW)*16 + m] = 2047 - (int)(slot_ & 0x7FFu); }

// double-precision named top-8 (phase 4)
#define CSWD(hi,lo) { \
    const bool sw_ = bet_d(dv##lo,di##lo,dv##hi,di##hi); \
    const double td_ = dv##hi; const int tj_ = di##hi; \
    dv##hi = sw_?dv##lo:dv##hi; di##hi = sw_?di##lo:di##hi; \
    dv##lo = sw_?td_:dv##lo;    di##lo = sw_?tj_:di##lo; }

#define INS8D(W,CI) \
    if (bet_d(W,CI,dv7,di7)) { dv7=(W); di7=(CI); \
        CSWD(6,7) CSWD(5,6) CSWD(4,5) CSWD(3,4) CSWD(2,3) CSWD(1,2) CSWD(0,1) }

// ======================= Kernel 0: pool prep =======================
// Normalize pools 0..3 of emb (8192 rows), fold in LOG2E, pack bf16 -> d_ws.
__global__ __launch_bounds__(256)
void prep_k(const float* __restrict__ emb, ushort* __restrict__ ebf)
{
    const int row = blockIdx.x*256 + threadIdx.x;   // 0..8191 (pools fqk,fv,rqk,rv)
    const float* src = emb + (size_t)row*DSP;
    float ss = 0.f;
    #pragma unroll
    for (int g=0; g<16; ++g) {
        const float4 v = *(const float4*)(src + g*4);
        ss += v.x*v.x + v.y*v.y + v.z*v.z + v.w*v.w;
    }
    const float inv = LOG2E_F / fmaxf(sqrtf(ss), 1e-12f);
    ushort* dst = ebf + (size_t)row*DSP;
    #pragma unroll
    for (int g=0; g<8; ++g) {
        const float4 a = *(const float4*)(src + g*8);
        const float4 b = *(const float4*)(src + g*8 + 4);
        uint4 o;
        o.x = packbf2(a.x*inv, a.y*inv);
        o.y = packbf2(a.z*inv, a.w*inv);
        o.z = packbf2(b.x*inv, b.y*inv);
        o.w = packbf2(b.z*inv, b.w*inv);
        *(uint4*)(dst + g*8) = o;
    }
}

// ======================= Kernel 1: fp64 VALU projection (R6-verified) =======================
// h written into the block's own output region:
//   h_hi f32 [64][64] at out+obase, h_lo bf16 [64][64] at out+obase+4096 floats.
#define PJROW(i) \
    a##i##0 = fma(xd##i, wd0, a##i##0); a##i##1 = fma(xd##i, wd1, a##i##1); \
    a##i##2 = fma(xd##i, wd2, a##i##2); a##i##3 = fma(xd##i, wd3, a##i##3);

#define EPI(i) { \
    const double v0_=a##i##0+bj0, v1_=a##i##1+bj1, v2_=a##i##2+bj2, v3_=a##i##3+bj3; \
    float4 hv; ushort4 lv; \
    hv.x=(float)v0_; hv.y=(float)v1_; hv.z=(float)v2_; hv.w=(float)v3_; \
    lv.x=f2bf((float)(v0_-(double)hv.x)); lv.y=f2bf((float)(v1_-(double)hv.y)); \
    lv.z=f2bf((float)(v2_-(double)hv.z)); lv.w=f2bf((float)(v3_-(double)hv.w)); \
    *(float4*) &hhi[(size_t)(rg*4+i)*64 + cg*4] = hv; \
    *(ushort4*)&hlo[(size_t)(rg*4+i)*64 + cg*4] = lv; }

__global__ __launch_bounds__(256, 3)
void proj_k(const float* __restrict__ x, const float* __restrict__ Wm,
            const float* __restrict__ bb, float* __restrict__ out)
{
    __shared__ __align__(16) float x_t[64*68];   // [k][row]
    __shared__ __align__(16) float w_t[64*68];   // [k][col]

    const int t    = threadIdx.x;
    const int cg   = t & 15;
    const int rg   = t >> 4;
    const int head = blockIdx.y;
    const int row0 = blockIdx.x * TILE_M;
    const size_t obase = ((size_t)head*NROWS + row0) * (size_t)NPOOL;

    double a00=0,a01=0,a02=0,a03=0, a10=0,a11=0,a12=0,a13=0,
           a20=0,a21=0,a22=0,a23=0, a30=0,a31=0,a32=0,a33=0;

    const int xr = t >> 2;        // 0..63 row
    const int xq = t & 3;         // k quarter (16 k's)
    const int wr = t >> 4;        // 0..15 base k-row for W
    const float* wbase = Wm + head*64 + cg*4;

    float4 xv0,xv1,xv2,xv3, wv0,wv1,wv2,wv3;
    {
        const float* xsrc = x + (size_t)(row0+xr)*DMODEL + xq*16;
        xv0 = *(const float4*)(xsrc);     xv1 = *(const float4*)(xsrc + 4);
        xv2 = *(const float4*)(xsrc + 8); xv3 = *(const float4*)(xsrc + 12);
        wv0 = *(const float4*)(wbase + (size_t)(wr     )*NPROJ);
        wv1 = *(const float4*)(wbase + (size_t)(wr + 16)*NPROJ);
        wv2 = *(const float4*)(wbase + (size_t)(wr + 32)*NPROJ);
        wv3 = *(const float4*)(wbase + (size_t)(wr + 48)*NPROJ);
    }

    for (int kk = 0; kk < DMODEL; kk += KT) {
        __syncthreads();   // prev tile's LDS reads done
        {
            const int k0 = xq*16;
            x_t[(k0+ 0)*68+xr]=xv0.x; x_t[(k0+ 1)*68+xr]=xv0.y; x_t[(k0+ 2)*68+xr]=xv0.z; x_t[(k0+ 3)*68+xr]=xv0.w;
            x_t[(k0+ 4)*68+xr]=xv1.x; x_t[(k0+ 5)*68+xr]=xv1.y; x_t[(k0+ 6)*68+xr]=xv1.z; x_t[(k0+ 7)*68+xr]=xv1.w;
            x_t[(k0+ 8)*68+xr]=xv2.x; x_t[(k0+ 9)*68+xr]=xv2.y; x_t[(k0+10)*68+xr]=xv2.z; x_t[(k0+11)*68+xr]=xv2.w;
            x_t[(k0+12)*68+xr]=xv3.x; x_t[(k0+13)*68+xr]=xv3.y; x_t[(k0+14)*68+xr]=xv3.z; x_t[(k0+15)*68+xr]=xv3.w;
            *(float4*)&w_t[(wr     )*68 + cg*4] = wv0;
            *(float4*)&w_t[(wr + 16)*68 + cg*4] = wv1;
            *(float4*)&w_t[(wr + 32)*68 + cg*4] = wv2;
            *(float4*)&w_t[(wr + 48)*68 + cg*4] = wv3;
        }
        __syncthreads();
        if (kk + KT < DMODEL) {   // prefetch next tile
            const float* xsrc = x + (size_t)(row0+xr)*DMODEL + (kk+KT) + xq*16;
            xv0 = *(const float4*)(xsrc);     xv1 = *(const float4*)(xsrc + 4);
            xv2 = *(const float4*)(xsrc + 8); xv3 = *(const float4*)(xsrc + 12);
            wv0 = *(const float4*)(wbase + (size_t)(kk+KT + wr     )*NPROJ);
            wv1 = *(const float4*)(wbase + (size_t)(kk+KT + wr + 16)*NPROJ);
            wv2 = *(const float4*)(wbase + (size_t)(kk+KT + wr + 32)*NPROJ);
            wv3 = *(const float4*)(wbase + (size_t)(kk+KT + wr + 48)*NPROJ);
        }
        #pragma unroll 4
        for (int k=0;k<KT;k++) {
            const float4 xf = *(const float4*)&x_t[k*68 + rg*4];
            const float4 wf = *(const float4*)&w_t[k*68 + cg*4];
            const double xd0=(double)xf.x, xd1=(double)xf.y, xd2=(double)xf.z, xd3=(double)xf.w;
            const double wd0=(double)wf.x, wd1=(double)wf.y, wd2=(double)wf.z, wd3=(double)wf.w;
            PJROW(0) PJROW(1) PJROW(2) PJROW(3)
        }
    }

    float*  hhi = out + obase;                       // [64][64] f32
    ushort* hlo = (ushort*)(out + obase + 4096);     // [64][64] bf16
    const double bj0=(double)bb[head*64+cg*4+0], bj1=(double)bb[head*64+cg*4+1];
    const double bj2=(double)bb[head*64+cg*4+2], bj3=(double)bb[head*64+cg*4+3];
    EPI(0) EPI(1) EPI(2) EPI(3)
}

// ======================= Kernel 2: router =======================
__global__ __launch_bounds__(256, 3)
void route_k(const float* __restrict__ emb, const ushort* __restrict__ ebf,
             float* __restrict__ out)
{
    __shared__ int    ridx16[64*16];                 // 4096 B
    __shared__ float  zbuf[64];
    __shared__ double rv[64*17];                     // 8704 B
    __shared__ __align__(8) float final8[64*16];     // 4096 B

    const int t    = threadIdx.x;
    const int lane = t & 63, wv = t >> 6;
    const int m    = lane & 15, q = lane >> 4;
    const int head = blockIdx.y;
    const int row0 = blockIdx.x * TILE_M;
    const size_t obase = ((size_t)head*NROWS + row0) * (size_t)NPOOL;

    int psel = 0;                 // pools: [fqk,fqk,fv,rqk,rqk,rv]
    if (head >= 2) psel = 1;
    if (head >= 3) psel = 2;
    if (head >= 5) psel = 3;
    const float*  epool = emb + (size_t)psel * NPOOL * DSP;
    const ushort* ebase = ebf + (size_t)psel * NPOOL * DSP;

    // ---- A fragments: h rows of this wave, bf16, from h_hi scratch ----
    union FragU { unsigned int u[4]; short8 s; };
    FragU A0, A1;
    {
        const float* hr = out + obase + (size_t)(wv*16 + m)*64 + q*8;
        const float4 a0 = *(const float4*)(hr);
        const float4 a1 = *(const float4*)(hr + 4);
        const float4 a2 = *(const float4*)(hr + 32);
        const float4 a3 = *(const float4*)(hr + 36);
        A0.u[0]=packbf2(a0.x,a0.y); A0.u[1]=packbf2(a0.z,a0.w);
        A0.u[2]=packbf2(a1.x,a1.y); A0.u[3]=packbf2(a1.z,a1.w);
        A1.u[0]=packbf2(a2.x,a2.y); A1.u[1]=packbf2(a2.z,a2.w);
        A1.u[2]=packbf2(a3.x,a3.y); A1.u[3]=packbf2(a3.z,a3.w);
    }

    // ---- Phase 1: MFMA logits, Z, per-lane packed top-8 ----
    DECL8P(0) DECL8P(1) DECL8P(2) DECL8P(3)
    float zacc0=0.f, zacc1=0.f, zacc2=0.f, zacc3=0.f;

    #pragma unroll 1
    for (int it=0; it<128; ++it) {
        const int cidx = it*16 + m;                 // e row this lane needs
        const unsigned invc = (unsigned)(2047 - cidx);
        const ushort* ep = ebase + (size_t)cidx*DSP + q*8;
        const short8 B0 = *(const short8*)(ep);
        const short8 B1 = *(const short8*)(ep + 32);

        f32x4 cc = {0.f,0.f,0.f,0.f};
        cc = __builtin_amdgcn_mfma_f32_16x16x32_bf16(A0.s, B0, cc, 0, 0, 0);
        cc = __builtin_amdgcn_mfma_f32_16x16x32_bf16(A1.s, B1, cc, 0, 0, 0);

        // raw v_exp_f32: args in [-25,-4], always normal -> bit-identical to libm
        #define PH1(r) { const float w_ = cc[r]; \
            zacc##r += __builtin_amdgcn_exp2f(w_ - C2); \
            unsigned u_ = __float_as_uint(w_); \
            u_ ^= ((unsigned)((int)u_ >> 31)) | 0x80000000u; \
            const unsigned p_ = (u_ & 0xFFFFF800u) | invc; \
            INS8P(r, p_) }
        PH1(0) PH1(1) PH1(2) PH1(3)
        #undef PH1
    }

    // ---- Z reduce over the 16 col-lanes of each row ----
    { float z=zacc0; z+=__shfl_xor(z,1,64); z+=__shfl_xor(z,2,64); z+=__shfl_xor(z,4,64); z+=__shfl_xor(z,8,64); if(m==0) zbuf[wv*16+q*4+0]=z; }
    { float z=zacc1; z+=__shfl_xor(z,1,64); z+=__shfl_xor(z,2,64); z+=__shfl_xor(z,4,64); z+=__shfl_xor(z,8,64); if(m==0) zbuf[wv*16+q*4+1]=z; }
    { float z=zacc2; z+=__shfl_xor(z,1,64); z+=__shfl_xor(z,2,64); z+=__shfl_xor(z,4,64); z+=__shfl_xor(z,8,64); if(m==0) zbuf[wv*16+q*4+2]=z; }
    { float z=zacc3; z+=__shfl_xor(z,1,64); z+=__shfl_xor(z,2,64); z+=__shfl_xor(z,4,64); z+=__shfl_xor(z,8,64); if(m==0) zbuf[wv*16+q*4+3]=z; }

    // ---- in-wave tournament: per-row top-16 into ridx16 (sorted desc) ----
    TOURNP(0, wv*16 + q*4 + 0)
    TOURNP(1, wv*16 + q*4 + 1)
    TOURNP(2, wv*16 + q*4 + 2)
    TOURNP(3, wv*16 + q*4 + 3)
    __syncthreads();

    // ---- Phase 3: fp64 rescore of the 16 candidates per row ----
    {
        const int row = t >> 2, q4 = t & 3;   // 4 candidates per thread
        const int ix0 = ridx16[row*16 + q4*4 + 0];
        const int ix1 = ridx16[row*16 + q4*4 + 1];
        const int ix2 = ridx16[row*16 + q4*4 + 2];
        const int ix3 = ridx16[row*16 + q4*4 + 3];
        const float* ep0 = epool + (size_t)ix0*DSP;
        const float* ep1 = epool + (size_t)ix1*DSP;
        const float* ep2 = epool + (size_t)ix2*DSP;
        const float* ep3 = epool + (size_t)ix3*DSP;
        const float*  hhr = out + obase + (size_t)row*64;
        const ushort* hlr = (const ushort*)(out + obase + 4096) + (size_t)row*64;
        double nn0=0,nn1=0,nn2=0,nn3=0, dd0=0,dd1=0,dd2=0,dd3=0;
        #pragma unroll 1
        for (int k4=0; k4<DSP; k4+=4) {
            const double h0 = (double)hhr[k4+0] + (double)bf2f(hlr[k4+0]);
            const double h1 = (double)hhr[k4+1] + (double)bf2f(hlr[k4+1]);
            const double h2 = (double)hhr[k4+2] + (double)bf2f(hlr[k4+2]);
            const double h3 = (double)hhr[k4+3] + (double)bf2f(hlr[k4+3]);
            #define RS(s) { const float4 e_ = *(const float4*)(ep##s + k4); \
                const double e0_=(double)e_.x, e1_=(double)e_.y, e2_=(double)e_.z, e3_=(double)e_.w; \
                nn##s += e0_*e0_ + e1_*e1_ + e2_*e2_ + e3_*e3_; \
                dd##s += h0*e0_ + h1*e1_ + h2*e2_ + h3*e3_; }
            RS(0) RS(1) RS(2) RS(3)
            #undef RS
        }
        rv[row*17 + q4*4 + 0] = dd0 / fmax(sqrt(nn0), 1e-12);
        rv[row*17 + q4*4 + 1] = dd1 / fmax(sqrt(nn1), 1e-12);
        rv[row*17 + q4*4 + 2] = dd2 / fmax(sqrt(nn2), 1e-12);
        rv[row*17 + q4*4 + 3] = dd3 / fmax(sqrt(nn3), 1e-12);
    }
    __syncthreads();

    // ---- Phase 4: fp64 top-8 select (named scalars), normalize, stash in LDS ----
    if (t < 64) {
        const float Zg = zbuf[t];
        double dv0=-INFINITY,dv1=-INFINITY,dv2=-INFINITY,dv3=-INFINITY,
               dv4=-INFINITY,dv5=-INFINITY,dv6=-INFINITY,dv7=-INFINITY;
        int    di0=IMAX,di1=IMAX,di2=IMAX,di3=IMAX,di4=IMAX,di5=IMAX,di6=IMAX,di7=IMAX;
        #pragma unroll 1
        for (int s=0;s<KEEP;s++) {
            const double v_  = rv[t*17 + s];
            const int    ix_ = ridx16[t*16 + s];
            INS8D(v_, ix_)
        }
        float denom = 1e-8f * Zg;
        const float ov0 = __builtin_amdgcn_exp2f((float)(dv0*LOG2E_D) - C2); denom += ov0;
        const float ov1 = __builtin_amdgcn_exp2f((float)(dv1*LOG2E_D) - C2); denom += ov1;
        const float ov2 = __builtin_amdgcn_exp2f((float)(dv2*LOG2E_D) - C2); denom += ov2;
        const float ov3 = __builtin_amdgcn_exp2f((float)(dv3*LOG2E_D) - C2); denom += ov3;
        const float ov4 = __builtin_amdgcn_exp2f((float)(dv4*LOG2E_D) - C2); denom += ov4;
        const float ov5 = __builtin_amdgcn_exp2f((float)(dv5*LOG2E_D) - C2); denom += ov5;
        const float ov6 = __builtin_amdgcn_exp2f((float)(dv6*LOG2E_D) - C2); denom += ov6;
        const float ov7 = __builtin_amdgcn_exp2f((float)(dv7*LOG2E_D) - C2); denom += ov7;
        const float rd = 1.0f / denom;
        float2 p;
        p.x=ov0*rd; p.y=__int_as_float(di0); *(float2*)&final8[t*16 +  0] = p;
        p.x=ov1*rd; p.y=__int_as_float(di1); *(float2*)&final8[t*16 +  2] = p;
        p.x=ov2*rd; p.y=__int_as_float(di2); *(float2*)&final8[t*16 +  4] = p;
        p.x=ov3*rd; p.y=__int_as_float(di3); *(float2*)&final8[t*16 +  6] = p;
        p.x=ov4*rd; p.y=__int_as_float(di4); *(float2*)&final8[t*16 +  8] = p;
        p.x=ov5*rd; p.y=__int_as_float(di5); *(float2*)&final8[t*16 + 10] = p;
        p.x=ov6*rd; p.y=__int_as_float(di6); *(float2*)&final8[t*16 + 12] = p;
        p.x=ov7*rd; p.y=__int_as_float(di7); *(float2*)&final8[t*16 + 14] = p;
    }
    __syncthreads();   // drains rescore loads + final8 stores before overwrite

    // ---- Phase 5: merged zero+scatter burst write (R0-verified; one visit per line) ----
    #pragma unroll 1
    for (int rr=0; rr<16; ++rr) {
        const int row = rr*4 + wv;          // one row per wave
        const float* fb = &final8[row*16];  // broadcast LDS reads
        const float pv0=fb[ 0]; const int pi0=__float_as_int(fb[ 1]);
        const float pv1=fb[ 2]; const int pi1=__float_as_int(fb[ 3]);
        const float pv2=fb[ 4]; const int pi2=__float_as_int(fb[ 5]);
        const float pv3=fb[ 6]; const int pi3=__float_as_int(fb[ 7]);
        const float pv4=fb[ 8]; const int pi4=__float_as_int(fb[ 9]);
        const float pv5=fb[10]; const int pi5=__float_as_int(fb[11]);
        const float pv6=fb[12]; const int pi6=__float_as_int(fb[13]);
        const float pv7=fb[14]; const int pi7=__float_as_int(fb[15]);
        float* orow = out + obase + (size_t)row*NPOOL;
        #pragma unroll
        for (int j=0;j<8;j++) {
            const int base4 = (j*64 + lane)*4;
            float v0=0.f, v1=0.f, v2=0.f, v3=0.f;
            #define SCAT(s) { const int d_ = pi##s - base4; \
                v0=(d_==0)?pv##s:v0; v1=(d_==1)?pv##s:v1; \
                v2=(d_==2)?pv##s:v2; v3=(d_==3)?pv##s:v3; }
            SCAT(0) SCAT(1) SCAT(2) SCAT(3) SCAT(4) SCAT(5) SCAT(6) SCAT(7)
            #undef SCAT
            *(float4*)&orow[base4] = make_float4(v0,v1,v2,v3);
        }
    }
}

extern "C" void kernel_launch(void* const* d_in, const int* in_sizes, int n_in,
                              void* d_out, int out_size, void* d_ws, size_t ws_size,
                              hipStream_t stream) {
    (void)in_sizes; (void)n_in; (void)ws_size; (void)out_size;
    const float* x   = (const float*)d_in[0];
    const float* Wm  = (const float*)d_in[1];
    const float* bb  = (const float*)d_in[2];
    const float* emb = (const float*)d_in[3];
    float*  out = (float*)d_out;
    ushort* ebf = (ushort*)d_ws;          // 4*2048*64 bf16 = 1 MB scratch
    dim3 grid(NROWS / TILE_M, HEADS);
    prep_k <<<32, 256, 0, stream>>>(emb, ebf);
    proj_k <<<grid, dim3(256), 0, stream>>>(x, Wm, bb, out);
    route_k<<<grid, dim3(256), 0, stream>>>(emb, ebf, out);
}

// Round 5
// 733.735 us; speedup vs baseline: 1.3131x; 1.0967x over previous
//
#include <hip/hip_runtime.h>
#include <hip/hip_bf16.h>
#include <math.h>

#define HEADS   6
#define DMODEL  1024
#define NPROJ   384
#define DSP     64
#define NPOOL   2048
#define NROWS   8192
#define TILE_M  64
#define KT      64
#define KEEP    16

#define LOG2E_F 1.44269504088896340f
#define LOG2E_D 1.4426950408889634
#define C2      14.4269504088896340f   /* 10*log2(e); |logit| provably < 10 */

#define NINF (-__builtin_inff())
#define IMAX 0x7fffffff

typedef __attribute__((ext_vector_type(8))) short  short8;
typedef __attribute__((ext_vector_type(4))) float  f32x4;
typedef __attribute__((ext_vector_type(4))) double f64x4;

__device__ __forceinline__ bool bet_d(double v, int vi, double w, int wi) {
    return (v > w) || (v == w && vi < wi);
}
__device__ __forceinline__ unsigned short f2bf(float f) {   // RNE, no NaN inputs
    unsigned int u = __float_as_uint(f);
    return (unsigned short)((u + 0x7fffu + ((u >> 16) & 1u)) >> 16);
}
__device__ __forceinline__ float bf2f(unsigned short s) {
    return __uint_as_float(((unsigned int)s) << 16);
}
__device__ __forceinline__ unsigned int packbf2(float a, float b) {
    return (unsigned int)f2bf(a) | ((unsigned int)f2bf(b) << 16);
}

// ---------- packed u32 top-8 machinery (R4-verified) ----------
#define DECL8P(r) \
    unsigned tp##r##0=0u,tp##r##1=0u,tp##r##2=0u,tp##r##3=0u, \
             tp##r##4=0u,tp##r##5=0u,tp##r##6=0u,tp##r##7=0u;

#define CSWP(r,hi,lo) { const unsigned a_=tp##r##hi, b_=tp##r##lo; \
    tp##r##hi = a_>b_?a_:b_; tp##r##lo = a_>b_?b_:a_; }

#define INS8P(r,P) \
    if ((P) > tp##r##7) { tp##r##7=(P); \
        CSWP(r,6,7) CSWP(r,5,6) CSWP(r,4,5) CSWP(r,3,4) \
        CSWP(r,2,3) CSWP(r,1,2) CSWP(r,0,1) }

#define TOURNP(r, ROW) { \
    unsigned slot_ = 0u; \
    for (int k_=0;k_<16;++k_) { \
        const unsigned my0_ = tp##r##0; \
        unsigned v_ = my0_; \
        { const unsigned o_=(unsigned)__shfl_xor((int)v_,1,64); v_ = v_>o_?v_:o_; } \
        { const unsigned o_=(unsigned)__shfl_xor((int)v_,2,64); v_ = v_>o_?v_:o_; } \
        { const unsigned o_=(unsigned)__shfl_xor((int)v_,4,64); v_ = v_>o_?v_:o_; } \
        { const unsigned o_=(unsigned)__shfl_xor((int)v_,8,64); v_ = v_>o_?v_:o_; } \
        const bool won_ = (v_ == my0_); \
        tp##r##0 = won_?tp##r##1:tp##r##0; \
        tp##r##1 = won_?tp##r##2:tp##r##1; \
        tp##r##2 = won_?tp##r##3:tp##r##2; \
        tp##r##3 = won_?tp##r##4:tp##r##3; \
        tp##r##4 = won_?tp##r##5:tp##r##4; \
        tp##r##5 = won_?tp##r##6:tp##r##5; \
        tp##r##6 = won_?tp##r##7:tp##r##6; \
        tp##r##7 = won_?0u:tp##r##7; \
        slot_ = (m==k_)?v_:slot_; \
    } \
    ridx16[(ROW)*16 + m] = 2047 - (int)(slot_ & 0x7FFu); }

// double-precision named top-8 (phase 4)
#define CSWD(hi,lo) { \
    const bool sw_ = bet_d(dv##lo,di##lo,dv##hi,di##hi); \
    const double td_ = dv##hi; const int tj_ = di##hi; \
    dv##hi = sw_?dv##lo:dv##hi; di##hi = sw_?di##lo:di##hi; \
    dv##lo = sw_?td_:dv##lo;    di##lo = sw_?tj_:di##lo; }

#define INS8D(W,CI) \
    if (bet_d(W,CI,dv7,di7)) { dv7=(W); di7=(CI); \
        CSWD(6,7) CSWD(5,6) CSWD(4,5) CSWD(3,4) CSWD(2,3) CSWD(1,2) CSWD(0,1) }

// ======================= Kernel 0: pool prep (R4-verified) =======================
__global__ __launch_bounds__(256)
void prep_k(const float* __restrict__ emb, ushort* __restrict__ ebf)
{
    const int row = blockIdx.x*256 + threadIdx.x;   // 0..8191 (pools fqk,fv,rqk,rv)
    const float* src = emb + (size_t)row*DSP;
    float ss = 0.f;
    #pragma unroll
    for (int g=0; g<16; ++g) {
        const float4 v = *(const float4*)(src + g*4);
        ss += v.x*v.x + v.y*v.y + v.z*v.z + v.w*v.w;
    }
    const float inv = LOG2E_F / fmaxf(sqrtf(ss), 1e-12f);
    ushort* dst = ebf + (size_t)row*DSP;
    #pragma unroll
    for (int g=0; g<8; ++g) {
        const float4 a = *(const float4*)(src + g*8);
        const float4 b = *(const float4*)(src + g*8 + 4);
        uint4 o;
        o.x = packbf2(a.x*inv, a.y*inv);
        o.y = packbf2(a.z*inv, a.w*inv);
        o.z = packbf2(b.x*inv, b.y*inv);
        o.w = packbf2(b.z*inv, b.w*inv);
        *(uint4*)(dst + g*8) = o;
    }
}

// ======================= Kernel 1: f64 MFMA projection, layout-probed =======================
// Staging identical to the verified VALU kernel. Each wave owns 16 rows
// (wv*16..+15) x 64 cols via 4 col-tiles of 16. Inner product uses
// v_mfma_f64_16x16x4: lane(q=lane>>4, m=lane&15) supplies A[m][k-slot q]
// and B[k-slot q][m] (standard, matches verified bf16 A-side convention).
// C/D lane->(row,col) mapping is NOT trusted: it is recovered at runtime by
// two probe MFMAs (exact small-integer arithmetic), so the epilogue is
// correct under ANY bijective (lane,reg)->(i,j) mapping.
__global__ __launch_bounds__(256, 3)
void proj_k(const float* __restrict__ x, const float* __restrict__ Wm,
            const float* __restrict__ bb, float* __restrict__ out)
{
    __shared__ __align__(16) float x_t[64*68];   // [k][row]
    __shared__ __align__(16) float w_t[64*68];   // [k][col]

    const int t    = threadIdx.x;
    const int lane = t & 63;
    const int wv   = t >> 6;          // wave id = 16-row tile
    const int m    = lane & 15;
    const int q    = lane >> 4;       // k-slot
    const int head = blockIdx.y;
    const int row0 = blockIdx.x * TILE_M;
    const size_t obase = ((size_t)head*NROWS + row0) * (size_t)NPOOL;

    // ---- C/D layout probes: D[i][j] = 4i  /  D[i][j] = 4j (exact) ----
    int pr0,pr1,pr2,pr3, pc0,pc1,pc2,pc3;
    {
        const f64x4 zz = {0.,0.,0.,0.};
        const f64x4 dpr = __builtin_amdgcn_mfma_f64_16x16x4f64((double)m, 1.0, zz, 0, 0, 0);
        const f64x4 dpc = __builtin_amdgcn_mfma_f64_16x16x4f64(1.0, (double)m, zz, 0, 0, 0);
        pr0=(int)(dpr[0]*0.25+0.5); pr1=(int)(dpr[1]*0.25+0.5);
        pr2=(int)(dpr[2]*0.25+0.5); pr3=(int)(dpr[3]*0.25+0.5);
        pc0=(int)(dpc[0]*0.25+0.5); pc1=(int)(dpc[1]*0.25+0.5);
        pc2=(int)(dpc[2]*0.25+0.5); pc3=(int)(dpc[3]*0.25+0.5);
    }

    f64x4 acc0 = {0.,0.,0.,0.}, acc1 = {0.,0.,0.,0.},
          acc2 = {0.,0.,0.,0.}, acc3 = {0.,0.,0.,0.};

    // staging roles (identical to verified kernel)
    const int xr = t >> 2;        // 0..63 row
    const int xq = t & 3;         // k quarter (16 k's)
    const int wr = t >> 4;        // 0..15 base k-row for W
    const int cg = t & 15;
    const float* wbase = Wm + head*64 + cg*4;

    float4 xv0,xv1,xv2,xv3, wv0,wv1,wv2,wv3;
    {
        const float* xsrc = x + (size_t)(row0+xr)*DMODEL + xq*16;
        xv0 = *(const float4*)(xsrc);     xv1 = *(const float4*)(xsrc + 4);
        xv2 = *(const float4*)(xsrc + 8); xv3 = *(const float4*)(xsrc + 12);
        wv0 = *(const float4*)(wbase + (size_t)(wr     )*NPROJ);
        wv1 = *(const float4*)(wbase + (size_t)(wr + 16)*NPROJ);
        wv2 = *(const float4*)(wbase + (size_t)(wr + 32)*NPROJ);
        wv3 = *(const float4*)(wbase + (size_t)(wr + 48)*NPROJ);
    }

    for (int kk = 0; kk < DMODEL; kk += KT) {
        __syncthreads();   // prev tile's LDS reads done
        {
            const int k0 = xq*16;
            x_t[(k0+ 0)*68+xr]=xv0.x; x_t[(k0+ 1)*68+xr]=xv0.y; x_t[(k0+ 2)*68+xr]=xv0.z; x_t[(k0+ 3)*68+xr]=xv0.w;
            x_t[(k0+ 4)*68+xr]=xv1.x; x_t[(k0+ 5)*68+xr]=xv1.y; x_t[(k0+ 6)*68+xr]=xv1.z; x_t[(k0+ 7)*68+xr]=xv1.w;
            x_t[(k0+ 8)*68+xr]=xv2.x; x_t[(k0+ 9)*68+xr]=xv2.y; x_t[(k0+10)*68+xr]=xv2.z; x_t[(k0+11)*68+xr]=xv2.w;
            x_t[(k0+12)*68+xr]=xv3.x; x_t[(k0+13)*68+xr]=xv3.y; x_t[(k0+14)*68+xr]=xv3.z; x_t[(k0+15)*68+xr]=xv3.w;
            *(float4*)&w_t[(wr     )*68 + cg*4] = wv0;
            *(float4*)&w_t[(wr + 16)*68 + cg*4] = wv1;
            *(float4*)&w_t[(wr + 32)*68 + cg*4] = wv2;
            *(float4*)&w_t[(wr + 48)*68 + cg*4] = wv3;
        }
        __syncthreads();
        if (kk + KT < DMODEL) {   // prefetch next tile
            const float* xsrc = x + (size_t)(row0+xr)*DMODEL + (kk+KT) + xq*16;
            xv0 = *(const float4*)(xsrc);     xv1 = *(const float4*)(xsrc + 4);
            xv2 = *(const float4*)(xsrc + 8); xv3 = *(const float4*)(xsrc + 12);
            wv0 = *(const float4*)(wbase + (size_t)(kk+KT + wr     )*NPROJ);
            wv1 = *(const float4*)(wbase + (size_t)(kk+KT + wr + 16)*NPROJ);
            wv2 = *(const float4*)(wbase + (size_t)(kk+KT + wr + 32)*NPROJ);
            wv3 = *(const float4*)(wbase + (size_t)(kk+KT + wr + 48)*NPROJ);
        }
        // 16 k-quads: lane supplies A[m][k=kb] and B[k=kb][col] with kb=kq*4+q
        #pragma unroll 4
        for (int kq = 0; kq < 16; ++kq) {
            const int kb = kq*4 + q;
            const double a  = (double)x_t[kb*68 + wv*16 + m];
            const double b0 = (double)w_t[kb*68 +      m];
            const double b1 = (double)w_t[kb*68 + 16 + m];
            const double b2 = (double)w_t[kb*68 + 32 + m];
            const double b3 = (double)w_t[kb*68 + 48 + m];
            acc0 = __builtin_amdgcn_mfma_f64_16x16x4f64(a, b0, acc0, 0, 0, 0);
            acc1 = __builtin_amdgcn_mfma_f64_16x16x4f64(a, b1, acc1, 0, 0, 0);
            acc2 = __builtin_amdgcn_mfma_f64_16x16x4f64(a, b2, acc2, 0, 0, 0);
            acc3 = __builtin_amdgcn_mfma_f64_16x16x4f64(a, b3, acc3, 0, 0, 0);
        }
    }

    // epilogue: coordinates from the probes -> correct under any C/D layout
    float*  hhi = out + obase;                       // [64][64] f32
    ushort* hlo = (ushort*)(out + obase + 4096);     // [64][64] bf16
    const float* bbp = bb + head*64;
    #pragma unroll
    for (int ct = 0; ct < 4; ++ct) {
        const f64x4 a4 = (ct==0)?acc0:(ct==1)?acc1:(ct==2)?acc2:acc3;
        #define WRB(r) { \
            const int row = wv*16 + pr##r; \
            const int col = ct*16 + pc##r; \
            const double v = a4[r] + (double)bbp[col]; \
            const float hi = (float)v; \
            hhi[(size_t)row*64 + col] = hi; \
            hlo[(size_t)row*64 + col] = f2bf((float)(v - (double)hi)); }
        WRB(0) WRB(1) WRB(2) WRB(3)
        #undef WRB
    }
}

// ======================= Kernel 2: router (R4-verified, unchanged) =======================
__global__ __launch_bounds__(256, 3)
void route_k(const float* __restrict__ emb, const ushort* __restrict__ ebf,
             float* __restrict__ out)
{
    __shared__ int    ridx16[64*16];                 // 4096 B
    __shared__ float  zbuf[64];
    __shared__ double rv[64*17];                     // 8704 B
    __shared__ __align__(8) float final8[64*16];     // 4096 B

    const int t    = threadIdx.x;
    const int lane = t & 63, wv = t >> 6;
    const int m    = lane & 15, q = lane >> 4;
    const int head = blockIdx.y;
    const int row0 = blockIdx.x * TILE_M;
    const size_t obase = ((size_t)head*NROWS + row0) * (size_t)NPOOL;

    int psel = 0;                 // pools: [fqk,fqk,fv,rqk,rqk,rv]
    if (head >= 2) psel = 1;
    if (head >= 3) psel = 2;
    if (head >= 5) psel = 3;
    const float*  epool = emb + (size_t)psel * NPOOL * DSP;
    const ushort* ebase = ebf + (size_t)psel * NPOOL * DSP;

    // ---- A fragments: h rows of this wave, bf16, from h_hi scratch ----
    union FragU { unsigned int u[4]; short8 s; };
    FragU A0, A1;
    {
        const float* hr = out + obase + (size_t)(wv*16 + m)*64 + q*8;
        const float4 a0 = *(const float4*)(hr);
        const float4 a1 = *(const float4*)(hr + 4);
        const float4 a2 = *(const float4*)(hr + 32);
        const float4 a3 = *(const float4*)(hr + 36);
        A0.u[0]=packbf2(a0.x,a0.y); A0.u[1]=packbf2(a0.z,a0.w);
        A0.u[2]=packbf2(a1.x,a1.y); A0.u[3]=packbf2(a1.z,a1.w);
        A1.u[0]=packbf2(a2.x,a2.y); A1.u[1]=packbf2(a2.z,a2.w);
        A1.u[2]=packbf2(a3.x,a3.y); A1.u[3]=packbf2(a3.z,a3.w);
    }

    // ---- Phase 1: MFMA logits, Z, per-lane packed top-8 ----
    DECL8P(0) DECL8P(1) DECL8P(2) DECL8P(3)
    float zacc0=0.f, zacc1=0.f, zacc2=0.f, zacc3=0.f;

    #pragma unroll 1
    for (int it=0; it<128; ++it) {
        const int cidx = it*16 + m;                 // e row this lane needs
        const unsigned invc = (unsigned)(2047 - cidx);
        const ushort* ep = ebase + (size_t)cidx*DSP + q*8;
        const short8 B0 = *(const short8*)(ep);
        const short8 B1 = *(const short8*)(ep + 32);

        f32x4 cc = {0.f,0.f,0.f,0.f};
        cc = __builtin_amdgcn_mfma_f32_16x16x32_bf16(A0.s, B0, cc, 0, 0, 0);
        cc = __builtin_amdgcn_mfma_f32_16x16x32_bf16(A1.s, B1, cc, 0, 0, 0);

        // raw v_exp_f32: args in [-25,-4], always normal -> bit-identical to libm
        #define PH1(r) { const float w_ = cc[r]; \
            zacc##r += __builtin_amdgcn_exp2f(w_ - C2); \
            unsigned u_ = __float_as_uint(w_); \
            u_ ^= ((unsigned)((int)u_ >> 31)) | 0x80000000u; \
            const unsigned p_ = (u_ & 0xFFFFF800u) | invc; \
            INS8P(r, p_) }
        PH1(0) PH1(1) PH1(2) PH1(3)
        #undef PH1
    }

    // ---- Z reduce over the 16 col-lanes of each row ----
    { float z=zacc0; z+=__shfl_xor(z,1,64); z+=__shfl_xor(z,2,64); z+=__shfl_xor(z,4,64); z+=__shfl_xor(z,8,64); if(m==0) zbuf[wv*16+q*4+0]=z; }
    { float z=zacc1; z+=__shfl_xor(z,1,64); z+=__shfl_xor(z,2,64); z+=__shfl_xor(z,4,64); z+=__shfl_xor(z,8,64); if(m==0) zbuf[wv*16+q*4+1]=z; }
    { float z=zacc2; z+=__shfl_xor(z,1,64); z+=__shfl_xor(z,2,64); z+=__shfl_xor(z,4,64); z+=__shfl_xor(z,8,64); if(m==0) zbuf[wv*16+q*4+2]=z; }
    { float z=zacc3; z+=__shfl_xor(z,1,64); z+=__shfl_xor(z,2,64); z+=__shfl_xor(z,4,64); z+=__shfl_xor(z,8,64); if(m==0) zbuf[wv*16+q*4+3]=z; }

    // ---- in-wave tournament: per-row top-16 into ridx16 (sorted desc) ----
    TOURNP(0, wv*16 + q*4 + 0)
    TOURNP(1, wv*16 + q*4 + 1)
    TOURNP(2, wv*16 + q*4 + 2)
    TOURNP(3, wv*16 + q*4 + 3)
    __syncthreads();

    // ---- Phase 3: fp64 rescore of the 16 candidates per row ----
    {
        const int row = t >> 2, q4 = t & 3;   // 4 candidates per thread
        const int ix0 = ridx16[row*16 + q4*4 + 0];
        const int ix1 = ridx16[row*16 + q4*4 + 1];
        const int ix2 = ridx16[row*16 + q4*4 + 2];
        const int ix3 = ridx16[row*16 + q4*4 + 3];
        const float* ep0 = epool + (size_t)ix0*DSP;
        const float* ep1 = epool + (size_t)ix1*DSP;
        const float* ep2 = epool + (size_t)ix2*DSP;
        const float* ep3 = epool + (size_t)ix3*DSP;
        const float*  hhr = out + obase + (size_t)row*64;
        const ushort* hlr = (const ushort*)(out + obase + 4096) + (size_t)row*64;
        double nn0=0,nn1=0,nn2=0,nn3=0, dd0=0,dd1=0,dd2=0,dd3=0;
        #pragma unroll 1
        for (int k4=0; k4<DSP; k4+=4) {
            const double h0 = (double)hhr[k4+0] + (double)bf2f(hlr[k4+0]);
            const double h1 = (double)hhr[k4+1] + (double)bf2f(hlr[k4+1]);
            const double h2 = (double)hhr[k4+2] + (double)bf2f(hlr[k4+2]);
            const double h3 = (double)hhr[k4+3] + (double)bf2f(hlr[k4+3]);
            #define RS(s) { const float4 e_ = *(const float4*)(ep##s + k4); \
                const double e0_=(double)e_.x, e1_=(double)e_.y, e2_=(double)e_.z, e3_=(double)e_.w; \
                nn##s += e0_*e0_ + e1_*e1_ + e2_*e2_ + e3_*e3_; \
                dd##s += h0*e0_ + h1*e1_ + h2*e2_ + h3*e3_; }
            RS(0) RS(1) RS(2) RS(3)
            #undef RS
        }
        rv[row*17 + q4*4 + 0] = dd0 / fmax(sqrt(nn0), 1e-12);
        rv[row*17 + q4*4 + 1] = dd1 / fmax(sqrt(nn1), 1e-12);
        rv[row*17 + q4*4 + 2] = dd2 / fmax(sqrt(nn2), 1e-12);
        rv[row*17 + q4*4 + 3] = dd3 / fmax(sqrt(nn3), 1e-12);
    }
    __syncthreads();

    // ---- Phase 4: fp64 top-8 select (named scalars), normalize, stash in LDS ----
    if (t < 64) {
        const float Zg = zbuf[t];
        double dv0=-INFINITY,dv1=-INFINITY,dv2=-INFINITY,dv3=-INFINITY,
               dv4=-INFINITY,dv5=-INFINITY,dv6=-INFINITY,dv7=-INFINITY;
        int    di0=IMAX,di1=IMAX,di2=IMAX,di3=IMAX,di4=IMAX,di5=IMAX,di6=IMAX,di7=IMAX;
        #pragma unroll 1
        for (int s=0;s<KEEP;s++) {
            const double v_  = rv[t*17 + s];
            const int    ix_ = ridx16[t*16 + s];
            INS8D(v_, ix_)
        }
        float denom = 1e-8f * Zg;
        const float ov0 = __builtin_amdgcn_exp2f((float)(dv0*LOG2E_D) - C2); denom += ov0;
        const float ov1 = __builtin_amdgcn_exp2f((float)(dv1*LOG2E_D) - C2); denom += ov1;
        const float ov2 = __builtin_amdgcn_exp2f((float)(dv2*LOG2E_D) - C2); denom += ov2;
        const float ov3 = __builtin_amdgcn_exp2f((float)(dv3*LOG2E_D) - C2); denom += ov3;
        const float ov4 = __builtin_amdgcn_exp2f((float)(dv4*LOG2E_D) - C2); denom += ov4;
        const float ov5 = __builtin_amdgcn_exp2f((float)(dv5*LOG2E_D) - C2); denom += ov5;
        const float ov6 = __builtin_amdgcn_exp2f((float)(dv6*LOG2E_D) - C2); denom += ov6;
        const float ov7 = __builtin_amdgcn_exp2f((float)(dv7*LOG2E_D) - C2); denom += ov7;
        const float rd = 1.0f / denom;
        float2 p;
        p.x=ov0*rd; p.y=__int_as_float(di0); *(float2*)&final8[t*16 +  0] = p;
        p.x=ov1*rd; p.y=__int_as_float(di1); *(float2*)&final8[t*16 +  2] = p;
        p.x=ov2*rd; p.y=__int_as_float(di2); *(float2*)&final8[t*16 +  4] = p;
        p.x=ov3*rd; p.y=__int_as_float(di3); *(float2*)&final8[t*16 +  6] = p;
        p.x=ov4*rd; p.y=__int_as_float(di4); *(float2*)&final8[t*16 +  8] = p;
        p.x=ov5*rd; p.y=__int_as_float(di5); *(float2*)&final8[t*16 + 10] = p;
        p.x=ov6*rd; p.y=__int_as_float(di6); *(float2*)&final8[t*16 + 12] = p;
        p.x=ov7*rd; p.y=__int_as_float(di7); *(float2*)&final8[t*16 + 14] = p;
    }
    __syncthreads();   // drains rescore loads + final8 stores before overwrite

    // ---- Phase 5: merged zero+scatter burst write (one visit per line) ----
    #pragma unroll 1
    for (int rr=0; rr<16; ++rr) {
        const int row = rr*4 + wv;          // one row per wave
        const float* fb = &final8[row*16];  // broadcast LDS reads
        const float pv0=fb[ 0]; const int pi0=__float_as_int(fb[ 1]);
        const float pv1=fb[ 2]; const int pi1=__float_as_int(fb[ 3]);
        const float pv2=fb[ 4]; const int pi2=__float_as_int(fb[ 5]);
        const float pv3=fb[ 6]; const int pi3=__float_as_int(fb[ 7]);
        const float pv4=fb[ 8]; const int pi4=__float_as_int(fb[ 9]);
        const float pv5=fb[10]; const int pi5=__float_as_int(fb[11]);
        const float pv6=fb[12]; const int pi6=__float_as_int(fb[13]);
        const float pv7=fb[14]; const int pi7=__float_as_int(fb[15]);
        float* orow = out + obase + (size_t)row*NPOOL;
        #pragma unroll
        for (int j=0;j<8;j++) {
            const int base4 = (j*64 + lane)*4;
            float v0=0.f, v1=0.f, v2=0.f, v3=0.f;
            #define SCAT(s) { const int d_ = pi##s - base4; \
                v0=(d_==0)?pv##s:v0; v1=(d_==1)?pv##s:v1; \
                v2=(d_==2)?pv##s:v2; v3=(d_==3)?pv##s:v3; }
            SCAT(0) SCAT(1) SCAT(2) SCAT(3) SCAT(4) SCAT(5) SCAT(6) SCAT(7)
            #undef SCAT
            *(float4*)&orow[base4] = make_float4(v0,v1,v2,v3);
        }
    }
}

extern "C" void kernel_launch(void* const* d_in, const int* in_sizes, int n_in,
                              void* d_out, int out_size, void* d_ws, size_t ws_size,
                              hipStream_t stream) {
    (void)in_sizes; (void)n_in; (void)ws_size; (void)out_size;
    const float* x   = (const float*)d_in[0];
    const float* Wm  = (const float*)d_in[1];
    const float* bb  = (const float*)d_in[2];
    const float* emb = (const float*)d_in[3];
    float*  out = (float*)d_out;
    ushort* ebf = (ushort*)d_ws;          // 4*2048*64 bf16 = 1 MB scratch
    dim3 grid(NROWS / TILE_M, HEADS);
    prep_k <<<32, 256, 0, stream>>>(emb, ebf);
    proj_k <<<grid, dim3(256), 0, stream>>>(x, Wm, bb, out);
    route_k<<<grid, dim3(256), 0, stream>>>(emb, ebf, out);
}